// Round 20
// baseline (134.777 us; speedup 1.0000x reference)
//
#include <hip/hip_runtime.h>
#include <math.h>

#define B 256
#define N 1152
#define C_ 10
#define OUT 16
#define IN 8
#define KO 160          // C_*OUT

// ---- s-partial geometry (R18 measured optimum): BT=4, KG=5, grid 4096
#define MB 16
#define NC 9
#define NCH 128         // slab 21 MB fp32
#define KG 5
#define XSTR 84

// partial[ch][b][k*16+o] = sum_{n in chunk} c[n,k]*(W[n,k,o,:].x[b,n,:])
// R20: #pragma unroll 2 on nl loop — R18 VGPR=64 showed no W-load pipelining (VALUBusy 26%).
__global__ __launch_bounds__(64, 4) void k_s_partial(
    const float* __restrict__ x, const float* __restrict__ W,
    const float* __restrict__ c, float* __restrict__ partial)
{
    __shared__ float xs[MB][XSTR];
    __shared__ float cs[NC][KG];

    const int tid = threadIdx.x;
    const int id  = blockIdx.x;
    const int g   = id & 7;
    const int q   = id >> 3;
    const int bt  = q & 15;
    const int kg  = (q >> 4) & 1;
    const int chl = q >> 5;
    const int ch  = g * 16 + chl;
    const int b0  = bt * MB;
    const int n0  = ch * NC;
    const int k0  = kg * KG;

    for (int idx = tid; idx < MB * 18; idx += 64) {
        int bl = idx / 18, r = idx - bl * 18;
        float4 val = *(const float4*)(x + (size_t)(b0 + bl) * (N * IN) + (size_t)n0 * IN + r * 4);
        *(float4*)(&xs[bl][r * 4]) = val;
    }
    if (c) {
        for (int idx = tid; idx < NC * KG; idx += 64) {
            int nl = idx / KG, kk = idx - nl * KG;
            cs[nl][kk] = c[(size_t)(n0 + nl) * C_ + (k0 + kk)];
        }
    }
    __syncthreads();

    const int o   = tid & 15;
    const int grp = (tid >> 4) * 4;

    float acc[4][KG];
#pragma unroll
    for (int r = 0; r < 4; ++r)
#pragma unroll
        for (int kk = 0; kk < KG; ++kk) acc[r][kk] = 0.f;

    const float* Wb = W + (size_t)n0 * (KO * IN) + (size_t)(k0 * OUT + o) * IN;

#pragma unroll 2
    for (int nl = 0; nl < NC; ++nl) {
        const float* Wn = Wb + (size_t)nl * (KO * IN);
        float4 w[KG][2];
#pragma unroll
        for (int kk = 0; kk < KG; ++kk) {
            w[kk][0] = *(const float4*)(Wn + kk * (OUT * IN));
            w[kk][1] = *(const float4*)(Wn + kk * (OUT * IN) + 4);
        }
        float4 xr[4][2];
#pragma unroll
        for (int r = 0; r < 4; ++r) {
            xr[r][0] = *(const float4*)(&xs[grp + r][nl * IN]);
            xr[r][1] = *(const float4*)(&xs[grp + r][nl * IN + 4]);
        }
        float cw[KG];
#pragma unroll
        for (int kk = 0; kk < KG; ++kk) cw[kk] = c ? cs[nl][kk] : 0.1f;

#pragma unroll
        for (int kk = 0; kk < KG; ++kk) {
#pragma unroll
            for (int r = 0; r < 4; ++r) {
                float d = w[kk][0].x * xr[r][0].x + w[kk][0].y * xr[r][0].y
                        + w[kk][0].z * xr[r][0].z + w[kk][0].w * xr[r][0].w
                        + w[kk][1].x * xr[r][1].x + w[kk][1].y * xr[r][1].y
                        + w[kk][1].z * xr[r][1].z + w[kk][1].w * xr[r][1].w;
                acc[r][kk] += cw[kk] * d;
            }
        }
    }

#pragma unroll
    for (int r = 0; r < 4; ++r) {
        float* pp = partial + (size_t)ch * (B * KO) + (size_t)(b0 + grp + r) * KO
                  + (size_t)k0 * OUT + o;
#pragma unroll
        for (int kk = 0; kk < KG; ++kk) pp[kk * OUT] = acc[r][kk];
    }
}

// ---------------- reduce partials over 128 chunks + squash, FLOAT4 version
// grid 160 x 256: block handles 64 float4 (256 elems); wave q sums chunks q*32..q*32+31
// (1 KB contiguous per wave per chunk access, was 256 B scalar)
__global__ __launch_bounds__(256) void k_reduce_squash(
    const float* __restrict__ partial, float* __restrict__ v, float* __restrict__ out)
{
    __shared__ float4 red[256];
    const int tid = threadIdx.x;
    const int f4  = blockIdx.x * 64 + (tid & 63);   // float4 index 0..10239
    const int q   = tid >> 6;                       // wave 0..3
    float4 s = make_float4(0.f, 0.f, 0.f, 0.f);
#pragma unroll
    for (int i = 0; i < NCH / 4; ++i) {
        float4 p = *(const float4*)(partial + (size_t)(q * (NCH / 4) + i) * (B * KO) + (size_t)f4 * 4);
        s.x += p.x; s.y += p.y; s.z += p.z; s.w += p.w;
    }
    red[tid] = s;
    __syncthreads();
    if (q == 0) {
        float4 a = red[tid], b2 = red[tid + 64], c2 = red[tid + 128], d2 = red[tid + 192];
        s.x = a.x + b2.x + c2.x + d2.x;
        s.y = a.y + b2.y + c2.y + d2.y;
        s.z = a.z + b2.z + c2.z + d2.z;
        s.w = a.w + b2.w + c2.w + d2.w;
        float4 vv;
        vv.x = s.x * fabsf(s.x) / (1.f + s.x * s.x);
        vv.y = s.y * fabsf(s.y) / (1.f + s.y * s.y);
        vv.z = s.z * fabsf(s.z) / (1.f + s.z * s.z);
        vv.w = s.w * fabsf(s.w) / (1.f + s.w * s.w);
        *(float4*)(v + (size_t)f4 * 4) = vv;
        if (out) *(float4*)(out + (size_t)f4 * 4) = vv;
    }
}

// ---------------- x transpose: xt[n][b][i] = x[b][n][i]  (once per launch)
__global__ __launch_bounds__(256) void k_xT(
    const float* __restrict__ x, float* __restrict__ xt)
{
    __shared__ float t[32][32 * IN + 4];
    const int bb0 = (blockIdx.x & 7) * 32;
    const int nn0 = (blockIdx.x >> 3) * 32;

    for (int idx = threadIdx.x; idx < 32 * 64; idx += 256) {
        int b = idx >> 6, r = idx & 63;
        float4 val = *(const float4*)(x + (size_t)(bb0 + b) * (N * IN) + (size_t)nn0 * IN + r * 4);
        *(float4*)(&t[b][r * 4]) = val;
    }
    __syncthreads();
    for (int idx = threadIdx.x; idx < 32 * 64; idx += 256) {
        int n = idx >> 6, r = idx & 63;
        int b = r >> 1, i = (r & 1) * 4;
        float4 val = *(const float4*)(&t[b][n * IN + i]);
        *(float4*)(xt + (size_t)(nn0 + n) * (B * IN) + (size_t)(bb0 + b) * IN + i) = val;
    }
}

// ---------------- a-pass + fused softmax (R16/R18-validated): W slice in 20 float4 regs,
// loaded AFTER the staging barrier; xt staged coalesced.
__global__ __launch_bounds__(256) void k_a_sm(
    const float* __restrict__ xt, const float* __restrict__ W,
    const float* __restrict__ v, float* __restrict__ bij,
    float* __restrict__ c_out, int accumulate)
{
    const int n = blockIdx.x;
    const int tid = threadIdx.x;

    __shared__ float xtl[B][IN];          // 8 KB
    __shared__ float red[4][16][C_];
    __shared__ float bnew[C_];

    const int o = tid & 15;
    const int blane = tid >> 4;

    {
        const float4* src = (const float4*)(xt + (size_t)n * (B * IN));
        for (int idx = tid; idx < B * IN / 4; idx += 256)
            *(float4*)(&xtl[idx >> 1][(idx & 1) * 4]) = src[idx];
    }
    __syncthreads();

    const float* Wb = W + (size_t)n * (KO * IN) + o * IN;
    float4 w0[C_], w1[C_];
#pragma unroll
    for (int k = 0; k < C_; ++k) {
        w0[k] = *(const float4*)(Wb + k * (OUT * IN));
        w1[k] = *(const float4*)(Wb + k * (OUT * IN) + 4);
    }

    float part[C_];
#pragma unroll
    for (int k = 0; k < C_; ++k) part[k] = 0.f;

    for (int t = 0; t < B / 16; ++t) {
        int bb = blane + t * 16;
        float4 xv0 = *(const float4*)(&xtl[bb][0]);
        float4 xv1 = *(const float4*)(&xtl[bb][4]);
        const float* vb = v + (size_t)bb * KO + o;
        float vv[C_];
#pragma unroll
        for (int k = 0; k < C_; ++k) vv[k] = vb[k * OUT];
#pragma unroll
        for (int k = 0; k < C_; ++k) {
            float d = w0[k].x * xv0.x + w0[k].y * xv0.y + w0[k].z * xv0.z + w0[k].w * xv0.w
                    + w1[k].x * xv1.x + w1[k].y * xv1.y + w1[k].z * xv1.z + w1[k].w * xv1.w;
            part[k] += d * vv[k];
        }
    }

    const int wv = tid >> 6;
#pragma unroll
    for (int k = 0; k < C_; ++k) {
        float p = part[k];
        p += __shfl_xor(p, 16);
        p += __shfl_xor(p, 32);
        part[k] = p;
    }
    if ((tid & 63) < 16) {
#pragma unroll
        for (int k = 0; k < C_; ++k) red[wv][o][k] = part[k];
    }
    __syncthreads();

    if (tid < C_) {
        float a = 0.f;
#pragma unroll
        for (int w = 0; w < 4; ++w)
#pragma unroll
            for (int oo = 0; oo < 16; ++oo) a += red[w][oo][tid];
        a *= (1.0f / B);
        float bo = accumulate ? bij[(size_t)n * C_ + tid] : 0.f;
        float bn = bo + a;
        bij[(size_t)n * C_ + tid] = bn;
        bnew[tid] = bn;
    }
    __syncthreads();
    if (tid < C_) {
        float m = -1e30f;
#pragma unroll
        for (int k = 0; k < C_; ++k) m = fmaxf(m, bnew[k]);
        float ssum = 0.f;
#pragma unroll
        for (int k = 0; k < C_; ++k) ssum += __expf(bnew[k] - m);
        c_out[(size_t)n * C_ + tid] = __expf(bnew[tid] - m) / ssum;
    }
}

extern "C" void kernel_launch(void* const* d_in, const int* in_sizes, int n_in,
                              void* d_out, int out_size, void* d_ws, size_t ws_size,
                              hipStream_t stream)
{
    const float* x = (const float*)d_in[0];   // [B, N, IN]
    const float* W = (const float*)d_in[1];   // [1, N, C, OUT, IN]
    float* out = (float*)d_out;               // [B, C, OUT, 1] = 40960 floats
    float* ws  = (float*)d_ws;

    float* part = ws;                         // 128 * 40960 = 5242880 floats (21 MB)
    float* bij  = ws + 5242880;               // 11520
    float* c    = bij + 11520;                // 11520
    float* v    = c + 11520;                  // 40960
    float* xt   = v + 40960;                  // 2359296 floats (9.4 MB)

    const int GS = 4096;                      // 8 XCD * 16 chl * 2 kg * 16 bt

    k_xT<<<288, 256, 0, stream>>>(x, xt);

    // iteration 0: c = 1/C exactly (softmax of zeros)
    k_s_partial<<<GS, 64, 0, stream>>>(x, W, nullptr, part);
    k_reduce_squash<<<160, 256, 0, stream>>>(part, v, nullptr);
    k_a_sm<<<N, 256, 0, stream>>>(xt, W, v, bij, c, 0);

    // iteration 1
    k_s_partial<<<GS, 64, 0, stream>>>(x, W, c, part);
    k_reduce_squash<<<160, 256, 0, stream>>>(part, v, nullptr);
    k_a_sm<<<N, 256, 0, stream>>>(xt, W, v, bij, c, 1);

    // iteration 2 (final: write d_out)
    k_s_partial<<<GS, 64, 0, stream>>>(x, W, c, part);
    k_reduce_squash<<<160, 256, 0, stream>>>(part, v, out);
}

// Round 21
// 128.825 us; speedup vs baseline: 1.0462x; 1.0462x over previous
//
#include <hip/hip_runtime.h>
#include <math.h>

#define B 256
#define N 1152
#define C_ 10
#define OUT 16
#define IN 8
#define KO 160          // C_*OUT

// ---- s-partial geometry (R10/R11/R18 measured optimum): BT=4, KG=5, grid 4096
// Consolidated laws: (a) grid 4096 / 16 one-wave blocks/CU / ~4MB/XCD footprint is the
// sweet spot — R9/R17 (more parallelism) and R16 (less) both regress hard; (b) no
// launch_bounds min-waves >4 (R3: forced spill); (c) no unroll pragma on nl loop and
// 640-block reduce (R20: both micro-opts regressed); (d) fp32 intermediates only
// (R19: fp16 slab+x fails threshold via routing feedback); (e) no grid.sync fusion
// (R14: ~100x a dispatch gap); (f) no atomicAdd accumulators (R12: serializes).
#define MB 16
#define NC 9
#define NCH 128         // slab 21 MB
#define KG 5
#define XSTR 84

// partial[ch][b][k*16+o] = sum_{n in chunk} c[n,k]*(W[n,k,o,:].x[b,n,:])
__global__ __launch_bounds__(64, 4) void k_s_partial(
    const float* __restrict__ x, const float* __restrict__ W,
    const float* __restrict__ c, float* __restrict__ partial)
{
    __shared__ float xs[MB][XSTR];
    __shared__ float cs[NC][KG];

    const int tid = threadIdx.x;
    const int id  = blockIdx.x;
    const int g   = id & 7;
    const int q   = id >> 3;
    const int bt  = q & 15;
    const int kg  = (q >> 4) & 1;
    const int chl = q >> 5;
    const int ch  = g * 16 + chl;
    const int b0  = bt * MB;
    const int n0  = ch * NC;
    const int k0  = kg * KG;

    for (int idx = tid; idx < MB * 18; idx += 64) {
        int bl = idx / 18, r = idx - bl * 18;
        float4 val = *(const float4*)(x + (size_t)(b0 + bl) * (N * IN) + (size_t)n0 * IN + r * 4);
        *(float4*)(&xs[bl][r * 4]) = val;
    }
    if (c) {
        for (int idx = tid; idx < NC * KG; idx += 64) {
            int nl = idx / KG, kk = idx - nl * KG;
            cs[nl][kk] = c[(size_t)(n0 + nl) * C_ + (k0 + kk)];
        }
    }
    __syncthreads();

    const int o   = tid & 15;
    const int grp = (tid >> 4) * 4;

    float acc[4][KG];
#pragma unroll
    for (int r = 0; r < 4; ++r)
#pragma unroll
        for (int kk = 0; kk < KG; ++kk) acc[r][kk] = 0.f;

    const float* Wb = W + (size_t)n0 * (KO * IN) + (size_t)(k0 * OUT + o) * IN;

    for (int nl = 0; nl < NC; ++nl) {
        const float* Wn = Wb + (size_t)nl * (KO * IN);
        float4 w[KG][2];
#pragma unroll
        for (int kk = 0; kk < KG; ++kk) {
            w[kk][0] = *(const float4*)(Wn + kk * (OUT * IN));
            w[kk][1] = *(const float4*)(Wn + kk * (OUT * IN) + 4);
        }
        float4 xr[4][2];
#pragma unroll
        for (int r = 0; r < 4; ++r) {
            xr[r][0] = *(const float4*)(&xs[grp + r][nl * IN]);
            xr[r][1] = *(const float4*)(&xs[grp + r][nl * IN + 4]);
        }
        float cw[KG];
#pragma unroll
        for (int kk = 0; kk < KG; ++kk) cw[kk] = c ? cs[nl][kk] : 0.1f;

#pragma unroll
        for (int kk = 0; kk < KG; ++kk) {
#pragma unroll
            for (int r = 0; r < 4; ++r) {
                float d = w[kk][0].x * xr[r][0].x + w[kk][0].y * xr[r][0].y
                        + w[kk][0].z * xr[r][0].z + w[kk][0].w * xr[r][0].w
                        + w[kk][1].x * xr[r][1].x + w[kk][1].y * xr[r][1].y
                        + w[kk][1].z * xr[r][1].z + w[kk][1].w * xr[r][1].w;
                acc[r][kk] += cw[kk] * d;
            }
        }
    }

#pragma unroll
    for (int r = 0; r < 4; ++r) {
        float* pp = partial + (size_t)ch * (B * KO) + (size_t)(b0 + grp + r) * KO
                  + (size_t)k0 * OUT + o;
#pragma unroll
        for (int kk = 0; kk < KG; ++kk) pp[kk * OUT] = acc[r][kk];
    }
}

// ---------------- reduce partials over 128 chunks + squash (proven, 640 blocks)
__global__ __launch_bounds__(256) void k_reduce_squash(
    const float* __restrict__ partial, float* __restrict__ v, float* __restrict__ out)
{
    __shared__ float red[256];
    const int tid = threadIdx.x;
    const int e   = blockIdx.x * 64 + (tid & 63);
    const int q   = tid >> 6;
    float s = 0.f;
#pragma unroll
    for (int i = 0; i < NCH / 4; ++i)
        s += partial[(size_t)(q * (NCH / 4) + i) * (B * KO) + e];
    red[tid] = s;
    __syncthreads();
    if (q == 0) {
        s = red[tid] + red[tid + 64] + red[tid + 128] + red[tid + 192];
        float vv = s * fabsf(s) / (1.f + s * s);
        v[e] = vv;
        if (out) out[e] = vv;
    }
}

// ---------------- x transpose: xt[n][b][i] = x[b][n][i]  (once per launch)
__global__ __launch_bounds__(256) void k_xT(
    const float* __restrict__ x, float* __restrict__ xt)
{
    __shared__ float t[32][32 * IN + 4];
    const int bb0 = (blockIdx.x & 7) * 32;
    const int nn0 = (blockIdx.x >> 3) * 32;

    for (int idx = threadIdx.x; idx < 32 * 64; idx += 256) {
        int b = idx >> 6, r = idx & 63;
        float4 val = *(const float4*)(x + (size_t)(bb0 + b) * (N * IN) + (size_t)nn0 * IN + r * 4);
        *(float4*)(&t[b][r * 4]) = val;
    }
    __syncthreads();
    for (int idx = threadIdx.x; idx < 32 * 64; idx += 256) {
        int n = idx >> 6, r = idx & 63;
        int b = r >> 1, i = (r & 1) * 4;
        float4 val = *(const float4*)(&t[b][n * IN + i]);
        *(float4*)(xt + (size_t)(nn0 + n) * (B * IN) + (size_t)(bb0 + b) * IN + i) = val;
    }
}

// ---------------- a-pass + fused softmax (R16/R18-validated): W slice in 20 float4 regs,
// loaded AFTER the staging barrier; xt staged coalesced.
__global__ __launch_bounds__(256) void k_a_sm(
    const float* __restrict__ xt, const float* __restrict__ W,
    const float* __restrict__ v, float* __restrict__ bij,
    float* __restrict__ c_out, int accumulate)
{
    const int n = blockIdx.x;
    const int tid = threadIdx.x;

    __shared__ float xtl[B][IN];          // 8 KB
    __shared__ float red[4][16][C_];
    __shared__ float bnew[C_];

    const int o = tid & 15;
    const int blane = tid >> 4;

    {
        const float4* src = (const float4*)(xt + (size_t)n * (B * IN));
        for (int idx = tid; idx < B * IN / 4; idx += 256)
            *(float4*)(&xtl[idx >> 1][(idx & 1) * 4]) = src[idx];
    }
    __syncthreads();

    const float* Wb = W + (size_t)n * (KO * IN) + o * IN;
    float4 w0[C_], w1[C_];
#pragma unroll
    for (int k = 0; k < C_; ++k) {
        w0[k] = *(const float4*)(Wb + k * (OUT * IN));
        w1[k] = *(const float4*)(Wb + k * (OUT * IN) + 4);
    }

    float part[C_];
#pragma unroll
    for (int k = 0; k < C_; ++k) part[k] = 0.f;

    for (int t = 0; t < B / 16; ++t) {
        int bb = blane + t * 16;
        float4 xv0 = *(const float4*)(&xtl[bb][0]);
        float4 xv1 = *(const float4*)(&xtl[bb][4]);
        const float* vb = v + (size_t)bb * KO + o;
        float vv[C_];
#pragma unroll
        for (int k = 0; k < C_; ++k) vv[k] = vb[k * OUT];
#pragma unroll
        for (int k = 0; k < C_; ++k) {
            float d = w0[k].x * xv0.x + w0[k].y * xv0.y + w0[k].z * xv0.z + w0[k].w * xv0.w
                    + w1[k].x * xv1.x + w1[k].y * xv1.y + w1[k].z * xv1.z + w1[k].w * xv1.w;
            part[k] += d * vv[k];
        }
    }

    const int wv = tid >> 6;
#pragma unroll
    for (int k = 0; k < C_; ++k) {
        float p = part[k];
        p += __shfl_xor(p, 16);
        p += __shfl_xor(p, 32);
        part[k] = p;
    }
    if ((tid & 63) < 16) {
#pragma unroll
        for (int k = 0; k < C_; ++k) red[wv][o][k] = part[k];
    }
    __syncthreads();

    if (tid < C_) {
        float a = 0.f;
#pragma unroll
        for (int w = 0; w < 4; ++w)
#pragma unroll
            for (int oo = 0; oo < 16; ++oo) a += red[w][oo][tid];
        a *= (1.0f / B);
        float bo = accumulate ? bij[(size_t)n * C_ + tid] : 0.f;
        float bn = bo + a;
        bij[(size_t)n * C_ + tid] = bn;
        bnew[tid] = bn;
    }
    __syncthreads();
    if (tid < C_) {
        float m = -1e30f;
#pragma unroll
        for (int k = 0; k < C_; ++k) m = fmaxf(m, bnew[k]);
        float ssum = 0.f;
#pragma unroll
        for (int k = 0; k < C_; ++k) ssum += __expf(bnew[k] - m);
        c_out[(size_t)n * C_ + tid] = __expf(bnew[tid] - m) / ssum;
    }
}

extern "C" void kernel_launch(void* const* d_in, const int* in_sizes, int n_in,
                              void* d_out, int out_size, void* d_ws, size_t ws_size,
                              hipStream_t stream)
{
    const float* x = (const float*)d_in[0];   // [B, N, IN]
    const float* W = (const float*)d_in[1];   // [1, N, C, OUT, IN]
    float* out = (float*)d_out;               // [B, C, OUT, 1] = 40960 floats
    float* ws  = (float*)d_ws;

    float* part = ws;                         // 128 * 40960 = 5242880 floats (21 MB)
    float* bij  = ws + 5242880;               // 11520
    float* c    = bij + 11520;                // 11520
    float* v    = c + 11520;                  // 40960
    float* xt   = v + 40960;                  // 2359296 floats (9.4 MB)

    const int GS = 4096;                      // 8 XCD * 16 chl * 2 kg * 16 bt

    k_xT<<<288, 256, 0, stream>>>(x, xt);

    // iteration 0: c = 1/C exactly (softmax of zeros)
    k_s_partial<<<GS, 64, 0, stream>>>(x, W, nullptr, part);
    k_reduce_squash<<<640, 256, 0, stream>>>(part, v, nullptr);
    k_a_sm<<<N, 256, 0, stream>>>(xt, W, v, bij, c, 0);

    // iteration 1
    k_s_partial<<<GS, 64, 0, stream>>>(x, W, c, part);
    k_reduce_squash<<<640, 256, 0, stream>>>(part, v, nullptr);
    k_a_sm<<<N, 256, 0, stream>>>(xt, W, v, bij, c, 1);

    // iteration 2 (final: write d_out)
    k_s_partial<<<GS, 64, 0, stream>>>(x, W, c, part);
    k_reduce_squash<<<640, 256, 0, stream>>>(part, v, out);
}